// Round 5
// baseline (348.431 us; speedup 1.0000x reference)
//
#include <hip/hip_runtime.h>

// PrimalCosAttention fused kernel. R5: barrier-free wave-private pipeline.
// B=4 H=12 N=4096 D=64 E=32. Grid = 48 bh x 16 = 768 blocks, 4 waves each.
// Each wave owns 16-row slabs end-to-end (norm -> GEMM1 -> S -> GEMM2) using
// wave-private LDS slabs: NO __syncthreads in the loop, so global stores are
// never drained by a barrier (the R4 regression). One barrier per block total
// (weight staging). Next-slab Q/K prefetched into registers.

namespace {
constexpr int Hh = 12;
constexpr int Nn = 4096;
// output offsets in floats
constexpr int O_ATTN = 0;
constexpr int O_ES   = 12582912;
constexpr int O_RS   = 18874368;
constexpr int O_WE   = 25165824;
constexpr int O_WR   = 25190400;
constexpr int O_Q    = 25214976;
constexpr int O_K    = 37797888;
constexpr int O_LAM  = 50380800;
}

typedef float  v4f  __attribute__((ext_vector_type(4)));
typedef __bf16 v8bf __attribute__((ext_vector_type(8)));

// fp32 -> bf16 round-to-nearest-even
__device__ __forceinline__ unsigned short f2b(float f) {
    unsigned int x = __float_as_uint(f);
    x += 0x7fffu + ((x >> 16) & 1u);
    return (unsigned short)(x >> 16);
}

// Swizzled index (ushorts) into [rows][64] bf16: 16B chunk ^= (row&7).
// Works for 16-row slabs and 64-row weight tiles alike.
__device__ __forceinline__ int swz(int row, int k) {
    return row * 64 + (((k >> 3) ^ (row & 7)) << 3) + (k & 7);
}

__global__ __launch_bounds__(256, 4)
void pca_fused(const float* __restrict__ Q, const float* __restrict__ Kp,
               const float* __restrict__ we, const float* __restrict__ wr,
               const float* __restrict__ mask, const float* __restrict__ W,
               const float* __restrict__ bias, const float* __restrict__ Lam,
               float* __restrict__ out)
{
    // 40 KiB LDS -> 4 blocks/CU
    __shared__ __align__(16) unsigned short WEs[2048];  // we_h^T [e 32][d 64]
    __shared__ __align__(16) unsigned short WRs[2048];  // wr_h^T [e 32][d 64]
    __shared__ __align__(16) unsigned short Ws_[4096];  // W      [d 64][e 64]
    __shared__ __align__(16) unsigned short Qsl[4096];  // 4 x wave-private 16x64
    __shared__ __align__(16) unsigned short Ksl[4096];
    __shared__ __align__(16) unsigned short Ssl[4096];

    const int tid = threadIdx.x;
    const int bh  = blockIdx.x >> 4;        // 0..47 (b*12+h)
    const int tb  = blockIdx.x & 15;        // 256-row group within (b,h)
    const int h   = bh % Hh;
    const int bb  = bh / Hh;

    // ---- passthrough outputs (we0 / wr0 / Lambda) ----
    if (blockIdx.x < 49) {
        int i4 = blockIdx.x * 256 + tid;
        if (i4 < 6144) {
            ((float4*)(out + O_WE))[i4] = ((const float4*)we)[i4];
        } else if (i4 < 12288) {
            ((float4*)(out + O_WR))[i4 - 6144] = ((const float4*)wr)[i4 - 6144];
        } else if (i4 < 12384) {
            ((float4*)(out + O_LAM))[i4 - 12288] = ((const float4*)Lam)[i4 - 12288];
        }
    }

    // ---- stage weights to bf16 LDS (once per block) ----
    {
        const float* weh = we + h * 2048;   // [d 64][e 32]
        const float* wrh = wr + h * 2048;
#pragma unroll
        for (int j = 0; j < 8; ++j) {
            int i = tid + 256 * j;
            int d = i >> 5, e = i & 31;
            WEs[swz(e, d)] = f2b(weh[i]);
            WRs[swz(e, d)] = f2b(wrh[i]);
        }
#pragma unroll
        for (int j = 0; j < 16; ++j) {
            int i = tid + 256 * j;          // W is [d 64][e2 64]
            int d = i >> 6, e = i & 63;
            Ws_[swz(d, e)] = f2b(W[i]);
        }
    }

    const int w    = tid >> 6;
    const int lane = tid & 63;
    const int quad = lane >> 4;
    const int n16  = lane & 15;
    unsigned short* Qs = Qsl + w * 1024;    // wave-private 16x64 slabs
    unsigned short* Ks = Ksl + w * 1024;
    unsigned short* Ss = Ssl + w * 1024;

    // load mapping: instr p covers rows 4p..4p+3; lane -> row 4p+(lane>>4),
    // elems (lane&15)*4 .. +3  (wave = 1024 contiguous bytes per instr)
    const int lr = lane >> 4;
    const int lc = (lane & 15) << 2;

    auto slab_base = [&](int it) {          // first global row of this wave's slab
        return tb * 256 + it * 64 + w * 16;
    };

    // ---- prefetch slab 0 ----
    float4 pq[4], pk[4];
    {
        int g0 = (bh * Nn + slab_base(0) + lr) * 64 + lc;
#pragma unroll
        for (int p = 0; p < 4; ++p) {
            pq[p] = *(const float4*)(Q  + g0 + p * 256);
            pk[p] = *(const float4*)(Kp + g0 + p * 256);
        }
    }

    // fragment load from a swizzled [.][64] bf16 matrix
    auto ldf = [&](const unsigned short* b, int row, int kb) -> v8bf {
        return *(const v8bf*)(b + row * 64 + ((((kb << 2) + quad) ^ (row & 7)) << 3));
    };

    float bv4[4];
#pragma unroll
    for (int nt = 0; nt < 4; ++nt) bv4[nt] = bias[nt * 16 + n16];

    __syncthreads();    // the only barrier: weights visible to all waves

    for (int it = 0; it < 4; ++it) {
        const int nb = slab_base(it);                 // global row base
        const int gt = (bh * Nn + nb) * 64;           // elem base

        // ---- normalize prefetched Q/K, write q/k fp32, stage bf16 slab ----
#pragma unroll
        for (int p = 0; p < 4; ++p) {
            int r = p * 4 + lr;                       // row in slab
            float4 q4 = pq[p], k4 = pk[p];
            float sq = q4.x*q4.x + q4.y*q4.y + q4.z*q4.z + q4.w*q4.w;
            float sk = k4.x*k4.x + k4.y*k4.y + k4.z*k4.z + k4.w*k4.w;
#pragma unroll
            for (int mm = 1; mm < 16; mm <<= 1) {     // 16 lanes hold one row
                sq += __shfl_xor(sq, mm, 64);
                sk += __shfl_xor(sk, mm, 64);
            }
            float iq = 1.0f / fmaxf(sqrtf(sq), 1e-12f);
            float ik = 1.0f / fmaxf(sqrtf(sk), 1e-12f);
            q4.x *= iq; q4.y *= iq; q4.z *= iq; q4.w *= iq;
            k4.x *= ik; k4.y *= ik; k4.z *= ik; k4.w *= ik;
            int g = gt + r * 64 + lc;
            *(float4*)(out + O_Q + g) = q4;
            *(float4*)(out + O_K + g) = k4;
            int a = swz(r, lc);                       // lc&7 in {0,4}: 8B aligned
            *(ushort4*)(Qs + a) = make_ushort4(f2b(q4.x), f2b(q4.y), f2b(q4.z), f2b(q4.w));
            *(ushort4*)(Ks + a) = make_ushort4(f2b(k4.x), f2b(k4.y), f2b(k4.z), f2b(k4.w));
        }

        // ---- prefetch next slab (pq/pk regs now free; overlaps compute) ----
        if (it + 1 < 4) {
            int gn = (bh * Nn + slab_base(it + 1) + lr) * 64 + lc;
#pragma unroll
            for (int p = 0; p < 4; ++p) {
                pq[p] = *(const float4*)(Q  + gn + p * 256);
                pk[p] = *(const float4*)(Kp + gn + p * 256);
            }
        }

        // ---- GEMM1: escore = Qn @ we_h, rscore = Kn @ wr_h (wave-private) ----
        v8bf aq0 = ldf(Qs, n16, 0), aq1 = ldf(Qs, n16, 1);
        v8bf ak0 = ldf(Ks, n16, 0), ak1 = ldf(Ks, n16, 1);
        v4f accE[2], accR[2];
#pragma unroll
        for (int nt = 0; nt < 2; ++nt) {
            int er = nt * 16 + n16;
            accE[nt] = (v4f){0.f, 0.f, 0.f, 0.f};
            accR[nt] = (v4f){0.f, 0.f, 0.f, 0.f};
            accE[nt] = __builtin_amdgcn_mfma_f32_16x16x32_bf16(aq0, ldf(WEs, er, 0), accE[nt], 0, 0, 0);
            accE[nt] = __builtin_amdgcn_mfma_f32_16x16x32_bf16(aq1, ldf(WEs, er, 1), accE[nt], 0, 0, 0);
            accR[nt] = __builtin_amdgcn_mfma_f32_16x16x32_bf16(ak0, ldf(WRs, er, 0), accR[nt], 0, 0, 0);
            accR[nt] = __builtin_amdgcn_mfma_f32_16x16x32_bf16(ak1, ldf(WRs, er, 1), accR[nt], 0, 0, 0);
        }

        // ---- write es/rs fp32; stage S=[es|rs] bf16 into Ss (wave-private) ----
        // C-layout: col = n16, row = quad*4 + i
#pragma unroll
        for (int nt = 0; nt < 2; ++nt) {
#pragma unroll
            for (int i = 0; i < 4; ++i) {
                int r = quad * 4 + i;
                int n = nb + r;
                out[O_ES + (bh * Nn + n) * 32 + nt * 16 + n16] = accE[nt][i];
                out[O_RS + (bh * Nn + n) * 32 + nt * 16 + n16] = accR[nt][i];
                Ss[swz(r, nt * 16 + n16)]      = f2b(accE[nt][i]);
                Ss[swz(r, 32 + nt * 16 + n16)] = f2b(accR[nt][i]);
            }
        }

        // ---- GEMM2: attn = S @ W^T + b (wave-private, no barrier) ----
        v8bf as0 = ldf(Ss, n16, 0), as1 = ldf(Ss, n16, 1);
        v4f accD[4];
#pragma unroll
        for (int nt = 0; nt < 4; ++nt) {
            float bv = bv4[nt];
            accD[nt] = (v4f){bv, bv, bv, bv};
            accD[nt] = __builtin_amdgcn_mfma_f32_16x16x32_bf16(as0, ldf(Ws_, nt * 16 + n16, 0), accD[nt], 0, 0, 0);
            accD[nt] = __builtin_amdgcn_mfma_f32_16x16x32_bf16(as1, ldf(Ws_, nt * 16 + n16, 1), accD[nt], 0, 0, 0);
        }

        float mv[4];
#pragma unroll
        for (int i = 0; i < 4; ++i) mv[i] = mask[bb * Nn + nb + quad * 4 + i];
#pragma unroll
        for (int nt = 0; nt < 4; ++nt) {
#pragma unroll
            for (int i = 0; i < 4; ++i) {
                int n = nb + quad * 4 + i;
                out[O_ATTN + (bh * Nn + n) * 64 + nt * 16 + n16] = accD[nt][i] * mv[i];
            }
        }
    }
}

extern "C" void kernel_launch(void* const* d_in, const int* in_sizes, int n_in,
                              void* d_out, int out_size, void* d_ws, size_t ws_size,
                              hipStream_t stream) {
    const float* Q    = (const float*)d_in[0];
    const float* Kp   = (const float*)d_in[1];
    const float* we   = (const float*)d_in[2];
    const float* wr   = (const float*)d_in[3];
    const float* mask = (const float*)d_in[4];
    const float* W    = (const float*)d_in[5];
    const float* bias = (const float*)d_in[6];
    const float* Lam  = (const float*)d_in[7];
    float* out = (float*)d_out;

    pca_fused<<<dim3(48 * 16), dim3(256), 0, stream>>>(Q, Kp, we, wr, mask, W, bias, Lam, out);
}